// Round 5
// baseline (92.279 us; speedup 1.0000x reference)
//
#include <hip/hip_runtime.h>

#define KP 137
#define SS 512
#define BB 128
#define THREADS 256
#define STRIP 8
#define NBLK 2048            // 2048 blocks x 4 waves = 8192 waves = 128 b x 64 strips

// Lane -> keypoint mapping (3 overlapped batches so every bone pair is
// intra-batch): batch a = kp lane (0..63), batch b = kp 63+lane (63..126),
// batch c = kp 126+lane for lane<=10 (126..136).
// Pose counted once: a lanes 0..63, b lanes 1..63, c lanes 1..10.
// Bone pairs: a lane<63 (k 0..62), b lane<63 (k 63..125), c lane<10 (k 126..135).

__global__ __launch_bounds__(THREADS, 8) void t2p_fused(
    const float* __restrict__ pred,      // [B,S,2K]
    const float* __restrict__ tgt,       // [B,2,S,K]
    const int*   __restrict__ tlen,      // [B]
    float2* __restrict__ partials,       // [NBLK]
    int* __restrict__ cnt,               // zeroed each launch
    float* __restrict__ out)             // [3]
{
    __shared__ float2 wsum[4];
    __shared__ int lastFlag;

    const int t    = threadIdx.x;
    const int lane = t & 63;
    const int wid  = t >> 6;
    const int w    = blockIdx.x * 4 + wid;   // 0..8191
    const int b    = w >> 6;                 // 64 strips per batch row
    const int s0   = (w & 63) * STRIP;
    const int len  = tlen[b];

    float pose = 0.f, bone = 0.f;

    if (s0 < len) {
        const int send = (len < s0 + STRIP) ? len : (s0 + STRIP);
        const float* txp = tgt + (size_t)(2 * b) * SS * KP;
        const float* typ = txp + (size_t)SS * KP;
        const float2* pp = (const float2*)(pred + (size_t)b * SS * (2 * KP));
        const bool lc = (lane <= 10);

        // rolling same-row target (row s0)
        float t0xa, t0xb, t0xc, t0ya, t0yb, t0yc;
        {
            const float* r = txp + s0 * KP;
            const float* q = typ + s0 * KP;
            t0xa = r[lane]; t0xb = r[63 + lane]; t0xc = lc ? r[126 + lane] : 0.f;
            t0ya = q[lane]; t0yb = q[63 + lane]; t0yc = lc ? q[126 + lane] : 0.f;
        }

        for (int u = s0; u < send; u += 2) {
            const int u1 = (u + 1 < SS) ? u + 1 : SS - 1;   // clamp only at u=511
            const int u2 = (u + 2 < SS) ? u + 2 : SS - 1;   // clamped rows unused

            // ---- issue ALL loads for both rows up front (18 VMEM in flight) ----
            const float2* pr0 = pp + (size_t)u  * KP;
            const float2* pr1 = pp + (size_t)u1 * KP;
            float2 p0a = pr0[lane], p0b = pr0[63 + lane];
            float2 p0c = lc ? pr0[126 + lane] : make_float2(0.f, 0.f);
            float2 p1a = pr1[lane], p1b = pr1[63 + lane];
            float2 p1c = lc ? pr1[126 + lane] : make_float2(0.f, 0.f);

            const float* r1 = txp + u1 * KP; const float* q1 = typ + u1 * KP;
            float t1xa = r1[lane], t1xb = r1[63 + lane], t1xc = lc ? r1[126 + lane] : 0.f;
            float t1ya = q1[lane], t1yb = q1[63 + lane], t1yc = lc ? q1[126 + lane] : 0.f;

            const float* r2 = txp + u2 * KP; const float* q2 = typ + u2 * KP;
            float t2xa = r2[lane], t2xb = r2[63 + lane], t2xc = lc ? r2[126 + lane] : 0.f;
            float t2ya = q2[lane], t2yb = q2[63 + lane], t2yc = lc ? q2[126 + lane] : 0.f;

            // ---- row u: pose vs t1, bone vs t0 ----
            if (u < len - 1) {
                float acc = fabsf(p0a.x - t1xa) + fabsf(p0a.y - t1ya);
                if (lane >= 1)       acc += fabsf(p0b.x - t1xb) + fabsf(p0b.y - t1yb);
                if (lane >= 1 && lc) acc += fabsf(p0c.x - t1xc) + fabsf(p0c.y - t1yc);
                pose += acc;
            }
            {
                float exa = p0a.x - t0xa, eya = p0a.y - t0ya;
                float exb = p0b.x - t0xb, eyb = p0b.y - t0yb;
                float exc = p0c.x - t0xc, eyc = p0c.y - t0yc;
                float nxa = __shfl_down(exa, 1, 64), nya = __shfl_down(eya, 1, 64);
                float nxb = __shfl_down(exb, 1, 64), nyb = __shfl_down(eyb, 1, 64);
                float nxc = __shfl_down(exc, 1, 64), nyc = __shfl_down(eyc, 1, 64);
                float acc = 0.f;
                if (lane < 63) {
                    float dx = nxa - exa, dy = nya - eya; acc += dx * dx + dy * dy;
                    float ex = nxb - exb, ey = nyb - eyb; acc += ex * ex + ey * ey;
                }
                if (lane < 10) {
                    float dx = nxc - exc, dy = nyc - eyc; acc += dx * dx + dy * dy;
                }
                bone += acc;
            }

            // ---- row u+1 (if inside strip): pose vs t2, bone vs t1 ----
            if (u + 1 < send) {
                if (u + 1 < len - 1) {
                    float acc = fabsf(p1a.x - t2xa) + fabsf(p1a.y - t2ya);
                    if (lane >= 1)       acc += fabsf(p1b.x - t2xb) + fabsf(p1b.y - t2yb);
                    if (lane >= 1 && lc) acc += fabsf(p1c.x - t2xc) + fabsf(p1c.y - t2yc);
                    pose += acc;
                }
                float exa = p1a.x - t1xa, eya = p1a.y - t1ya;
                float exb = p1b.x - t1xb, eyb = p1b.y - t1yb;
                float exc = p1c.x - t1xc, eyc = p1c.y - t1yc;
                float nxa = __shfl_down(exa, 1, 64), nya = __shfl_down(eya, 1, 64);
                float nxb = __shfl_down(exb, 1, 64), nyb = __shfl_down(eyb, 1, 64);
                float nxc = __shfl_down(exc, 1, 64), nyc = __shfl_down(eyc, 1, 64);
                float acc = 0.f;
                if (lane < 63) {
                    float dx = nxa - exa, dy = nya - eya; acc += dx * dx + dy * dy;
                    float ex = nxb - exb, ey = nyb - eyb; acc += ex * ex + ey * ey;
                }
                if (lane < 10) {
                    float dx = nxc - exc, dy = nyc - eyc; acc += dx * dx + dy * dy;
                }
                bone += acc;
            }

            // roll: target row u+2 becomes next iteration's same-row target
            t0xa = t2xa; t0xb = t2xb; t0xc = t2xc;
            t0ya = t2ya; t0yb = t2yb; t0yc = t2yc;
        }
    }

    // ---- block partial ----
    for (int off = 32; off > 0; off >>= 1) {
        pose += __shfl_down(pose, off, 64);
        bone += __shfl_down(bone, off, 64);
    }
    if (lane == 0) wsum[wid] = make_float2(pose, bone);
    __syncthreads();
    if (t == 0) {
        float px = 0.f, bx = 0.f;
        #pragma unroll
        for (int i = 0; i < 4; ++i) { px += wsum[i].x; bx += wsum[i].y; }
        partials[blockIdx.x] = make_float2(px, bx);
        __threadfence();                       // release partial (device scope)
        int old = atomicAdd(cnt, 1);
        lastFlag = (old == NBLK - 1);
    }
    __syncthreads();
    if (!lastFlag) return;

    // ---- last-arriving block folds everything (deterministic order) ----
    __threadfence();                           // acquire all partials
    float ps = 0.f, bs = 0.f;
    #pragma unroll
    for (int i = 0; i < NBLK / THREADS; ++i) {
        float2 v = partials[t + i * THREADS];
        ps += v.x; bs += v.y;
    }
    float pc = 0.f, mc = 0.f;
    if (t < BB) {
        int L = tlen[t];
        pc = (float)(L - 1);   // sum(pose_mask)
        mc = (float)L;         // sum(mask)
    }
    for (int off = 32; off > 0; off >>= 1) {
        ps += __shfl_down(ps, off, 64);
        bs += __shfl_down(bs, off, 64);
        pc += __shfl_down(pc, off, 64);
        mc += __shfl_down(mc, off, 64);
    }
    __shared__ float4 fsum[4];
    if (lane == 0) fsum[wid] = make_float4(ps, bs, pc, mc);
    __syncthreads();
    if (t == 0) {
        float4 a = fsum[0];
        #pragma unroll
        for (int i = 1; i < 4; ++i) {
            a.x += fsum[i].x; a.y += fsum[i].y;
            a.z += fsum[i].z; a.w += fsum[i].w;
        }
        float pose_loss = a.x / (274.f * a.z);
        float bone_loss = (a.y * 0.5f) / ((136.f + 1e-8f) * a.w);
        out[0] = pose_loss + 0.1f * bone_loss;   // POSE_W=1, BONE_W=0.1
        out[1] = pose_loss;
        out[2] = bone_loss;
    }
}

extern "C" void kernel_launch(void* const* d_in, const int* in_sizes, int n_in,
                              void* d_out, int out_size, void* d_ws, size_t ws_size,
                              hipStream_t stream) {
    const float* pred = (const float*)d_in[0];   // [128,512,274] f32
    const float* tgt  = (const float*)d_in[1];   // [128,2,512,137] f32
    const int*   tlen = (const int*)d_in[2];     // [128] i32
    float* out = (float*)d_out;

    float2* partials = (float2*)d_ws;                            // 16 KB
    int* cnt = (int*)((char*)d_ws + NBLK * sizeof(float2));      // 4 B counter

    hipMemsetAsync(cnt, 0, sizeof(int), stream);                 // deterministic
    t2p_fused<<<NBLK, THREADS, 0, stream>>>(pred, tgt, tlen, partials, cnt, out);
}

// Round 6
// 91.746 us; speedup vs baseline: 1.0058x; 1.0058x over previous
//
#include <hip/hip_runtime.h>

#define KP 137
#define SS 512
#define BB 128
#define THREADS 256
#define STRIP 8
#define NBLK 2048            // 2048 blocks x 4 waves = 8192 waves = 128 b x 64 strips

// Lane -> keypoint mapping (3 overlapped batches so every bone pair is
// intra-batch): batch a = kp lane (0..63), batch b = kp 63+lane (63..126),
// batch c = kp 126+lane for lane<=10 (126..136).
// Pose counted once: a lanes 0..63, b lanes 1..63, c lanes 1..10.
// Bone pairs: a lane<63 (k 0..62), b lane<63 (k 63..125), c lane<10 (k 126..135).

// NOTE: no min-waves arg — round 5 showed __launch_bounds__(256,8) caps VGPR
// at 28 and serializes all loads (130 us). ILP here needs ~60-90 VGPRs.
__global__ __launch_bounds__(THREADS) void t2p_fused(
    const float* __restrict__ pred,      // [B,S,2K]
    const float* __restrict__ tgt,       // [B,2,S,K]
    const int*   __restrict__ tlen,      // [B]
    float2* __restrict__ partials,       // [NBLK]
    int* __restrict__ cnt,               // zeroed each launch
    float* __restrict__ out)             // [3]
{
    __shared__ float2 wsum[4];
    __shared__ int lastFlag;

    const int t    = threadIdx.x;
    const int lane = t & 63;
    const int wid  = t >> 6;
    const int w    = blockIdx.x * 4 + wid;   // 0..8191
    const int b    = w >> 6;                 // 64 strips per batch row
    const int s0   = (w & 63) * STRIP;
    const int len  = tlen[b];

    float pose = 0.f, bone = 0.f;

    if (s0 < len) {
        const int send = (len < s0 + STRIP) ? len : (s0 + STRIP);
        const float* txp = tgt + (size_t)(2 * b) * SS * KP;
        const float* typ = txp + (size_t)SS * KP;
        const float2* pp = (const float2*)(pred + (size_t)b * SS * (2 * KP));
        const bool lc = (lane <= 10);

        // rolling same-row target (row s0)
        float t0xa, t0xb, t0xc, t0ya, t0yb, t0yc;
        {
            const float* r = txp + s0 * KP;
            const float* q = typ + s0 * KP;
            t0xa = r[lane]; t0xb = r[63 + lane]; t0xc = lc ? r[126 + lane] : 0.f;
            t0ya = q[lane]; t0yb = q[63 + lane]; t0yc = lc ? q[126 + lane] : 0.f;
        }

        for (int u = s0; u < send; u += 2) {
            const int u1 = (u + 1 < SS) ? u + 1 : SS - 1;   // clamp only at u=511
            const int u2 = (u + 2 < SS) ? u + 2 : SS - 1;   // clamped rows unused

            // ---- issue ALL loads for both rows up front (18 VMEM in flight) ----
            const float2* pr0 = pp + (size_t)u  * KP;
            const float2* pr1 = pp + (size_t)u1 * KP;
            float2 p0a = pr0[lane], p0b = pr0[63 + lane];
            float2 p0c = lc ? pr0[126 + lane] : make_float2(0.f, 0.f);
            float2 p1a = pr1[lane], p1b = pr1[63 + lane];
            float2 p1c = lc ? pr1[126 + lane] : make_float2(0.f, 0.f);

            const float* r1 = txp + u1 * KP; const float* q1 = typ + u1 * KP;
            float t1xa = r1[lane], t1xb = r1[63 + lane], t1xc = lc ? r1[126 + lane] : 0.f;
            float t1ya = q1[lane], t1yb = q1[63 + lane], t1yc = lc ? q1[126 + lane] : 0.f;

            const float* r2 = txp + u2 * KP; const float* q2 = typ + u2 * KP;
            float t2xa = r2[lane], t2xb = r2[63 + lane], t2xc = lc ? r2[126 + lane] : 0.f;
            float t2ya = q2[lane], t2yb = q2[63 + lane], t2yc = lc ? q2[126 + lane] : 0.f;

            // ---- row u: pose vs t1, bone vs t0 ----
            if (u < len - 1) {
                float acc = fabsf(p0a.x - t1xa) + fabsf(p0a.y - t1ya);
                if (lane >= 1)       acc += fabsf(p0b.x - t1xb) + fabsf(p0b.y - t1yb);
                if (lane >= 1 && lc) acc += fabsf(p0c.x - t1xc) + fabsf(p0c.y - t1yc);
                pose += acc;
            }
            {
                float exa = p0a.x - t0xa, eya = p0a.y - t0ya;
                float exb = p0b.x - t0xb, eyb = p0b.y - t0yb;
                float exc = p0c.x - t0xc, eyc = p0c.y - t0yc;
                float nxa = __shfl_down(exa, 1, 64), nya = __shfl_down(eya, 1, 64);
                float nxb = __shfl_down(exb, 1, 64), nyb = __shfl_down(eyb, 1, 64);
                float nxc = __shfl_down(exc, 1, 64), nyc = __shfl_down(eyc, 1, 64);
                float acc = 0.f;
                if (lane < 63) {
                    float dx = nxa - exa, dy = nya - eya; acc += dx * dx + dy * dy;
                    float ex = nxb - exb, ey = nyb - eyb; acc += ex * ex + ey * ey;
                }
                if (lane < 10) {
                    float dx = nxc - exc, dy = nyc - eyc; acc += dx * dx + dy * dy;
                }
                bone += acc;
            }

            // ---- row u+1 (if inside strip): pose vs t2, bone vs t1 ----
            if (u + 1 < send) {
                if (u + 1 < len - 1) {
                    float acc = fabsf(p1a.x - t2xa) + fabsf(p1a.y - t2ya);
                    if (lane >= 1)       acc += fabsf(p1b.x - t2xb) + fabsf(p1b.y - t2yb);
                    if (lane >= 1 && lc) acc += fabsf(p1c.x - t2xc) + fabsf(p1c.y - t2yc);
                    pose += acc;
                }
                float exa = p1a.x - t1xa, eya = p1a.y - t1ya;
                float exb = p1b.x - t1xb, eyb = p1b.y - t1yb;
                float exc = p1c.x - t1xc, eyc = p1c.y - t1yc;
                float nxa = __shfl_down(exa, 1, 64), nya = __shfl_down(eya, 1, 64);
                float nxb = __shfl_down(exb, 1, 64), nyb = __shfl_down(eyb, 1, 64);
                float nxc = __shfl_down(exc, 1, 64), nyc = __shfl_down(eyc, 1, 64);
                float acc = 0.f;
                if (lane < 63) {
                    float dx = nxa - exa, dy = nya - eya; acc += dx * dx + dy * dy;
                    float ex = nxb - exb, ey = nyb - eyb; acc += ex * ex + ey * ey;
                }
                if (lane < 10) {
                    float dx = nxc - exc, dy = nyc - eyc; acc += dx * dx + dy * dy;
                }
                bone += acc;
            }

            // roll: target row u+2 becomes next iteration's same-row target
            t0xa = t2xa; t0xb = t2xb; t0xc = t2xc;
            t0ya = t2ya; t0yb = t2yb; t0yc = t2yc;
        }
    }

    // ---- block partial ----
    for (int off = 32; off > 0; off >>= 1) {
        pose += __shfl_down(pose, off, 64);
        bone += __shfl_down(bone, off, 64);
    }
    if (lane == 0) wsum[wid] = make_float2(pose, bone);
    __syncthreads();
    if (t == 0) {
        float px = 0.f, bx = 0.f;
        #pragma unroll
        for (int i = 0; i < 4; ++i) { px += wsum[i].x; bx += wsum[i].y; }
        partials[blockIdx.x] = make_float2(px, bx);
        __threadfence();                       // release partial (device scope)
        int old = atomicAdd(cnt, 1);
        lastFlag = (old == NBLK - 1);
    }
    __syncthreads();
    if (!lastFlag) return;

    // ---- last-arriving block folds everything (deterministic order) ----
    __threadfence();                           // acquire all partials
    float ps = 0.f, bs = 0.f;
    #pragma unroll
    for (int i = 0; i < NBLK / THREADS; ++i) {
        float2 v = partials[t + i * THREADS];
        ps += v.x; bs += v.y;
    }
    float pc = 0.f, mc = 0.f;
    if (t < BB) {
        int L = tlen[t];
        pc = (float)(L - 1);   // sum(pose_mask)
        mc = (float)L;         // sum(mask)
    }
    for (int off = 32; off > 0; off >>= 1) {
        ps += __shfl_down(ps, off, 64);
        bs += __shfl_down(bs, off, 64);
        pc += __shfl_down(pc, off, 64);
        mc += __shfl_down(mc, off, 64);
    }
    __shared__ float4 fsum[4];
    if (lane == 0) fsum[wid] = make_float4(ps, bs, pc, mc);
    __syncthreads();
    if (t == 0) {
        float4 a = fsum[0];
        #pragma unroll
        for (int i = 1; i < 4; ++i) {
            a.x += fsum[i].x; a.y += fsum[i].y;
            a.z += fsum[i].z; a.w += fsum[i].w;
        }
        float pose_loss = a.x / (274.f * a.z);
        float bone_loss = (a.y * 0.5f) / ((136.f + 1e-8f) * a.w);
        out[0] = pose_loss + 0.1f * bone_loss;   // POSE_W=1, BONE_W=0.1
        out[1] = pose_loss;
        out[2] = bone_loss;
    }
}

extern "C" void kernel_launch(void* const* d_in, const int* in_sizes, int n_in,
                              void* d_out, int out_size, void* d_ws, size_t ws_size,
                              hipStream_t stream) {
    const float* pred = (const float*)d_in[0];   // [128,512,274] f32
    const float* tgt  = (const float*)d_in[1];   // [128,2,512,137] f32
    const int*   tlen = (const int*)d_in[2];     // [128] i32
    float* out = (float*)d_out;

    float2* partials = (float2*)d_ws;                            // 16 KB
    int* cnt = (int*)((char*)d_ws + NBLK * sizeof(float2));      // 4 B counter

    hipMemsetAsync(cnt, 0, sizeof(int), stream);                 // deterministic
    t2p_fused<<<NBLK, THREADS, 0, stream>>>(pred, tgt, tlen, partials, cnt, out);
}

// Round 7
// 23.581 us; speedup vs baseline: 3.9132x; 3.8906x over previous
//
#include <hip/hip_runtime.h>

#define KP 137
#define SS 512
#define BB 128
#define STRIP 4
#define NSTRIP (SS / STRIP)          // 128 strips per batch
#define NBLK (BB * NSTRIP)           // 16384 one-wave blocks

// Lane -> keypoint mapping (3 overlapped sub-batches so every bone pair is
// intra-sub-batch): a = kp lane (0..63), b = kp 63+lane (63..126),
// c = kp 126+lane for lane<=10 (126..136).
// Pose counted once: a lanes 0..63, b lanes 1..63, c lanes 1..10.
// Bone pairs: a lane<63 (k 0..62), b lane<63 (k 63..125), c lane<10 (k 126..135).

__global__ __launch_bounds__(64) void t2p_main(
    const float* __restrict__ pred,      // [B,S,2K]
    const float* __restrict__ tgt,       // [B,2,S,K]
    const int*   __restrict__ tlen,      // [B]
    float2* __restrict__ partials)       // [NBLK]
{
    const int lane = threadIdx.x;            // one wave per block
    const int w    = blockIdx.x;
    const int b    = w >> 7;                 // NSTRIP = 128 strips per batch
    const int s0   = (w & (NSTRIP - 1)) * STRIP;
    const int len  = tlen[b];

    float pose = 0.f, bone = 0.f;

    if (s0 < len) {
        const int send = (len < s0 + STRIP) ? len : (s0 + STRIP);
        const float* txp = tgt + (size_t)(2 * b) * SS * KP;   // x plane (SGPR base)
        const float* typ = txp + (size_t)SS * KP;             // y plane
        const float2* pp = (const float2*)(pred + (size_t)b * SS * (2 * KP));
        const bool lc = (lane <= 10);

        // rolling same-row target (row s0)
        float t0xa, t0xb, t0xc, t0ya, t0yb, t0yc;
        {
            const float* r = txp + s0 * KP;
            const float* q = typ + s0 * KP;
            t0xa = r[lane]; t0xb = r[63 + lane]; t0xc = lc ? r[126 + lane] : 0.f;
            t0ya = q[lane]; t0yb = q[63 + lane]; t0yc = lc ? q[126 + lane] : 0.f;
        }

        for (int s = s0; s < send; ++s) {
            const float2* pr = pp + (size_t)s * KP;
            float2 pa = pr[lane];
            float2 pb = pr[63 + lane];
            float2 pc = lc ? pr[126 + lane] : make_float2(0.f, 0.f);

            float t1xa = 0.f, t1xb = 0.f, t1xc = 0.f;
            float t1ya = 0.f, t1yb = 0.f, t1yc = 0.f;
            if (s + 1 < SS) {                 // uniform branch
                const float* r = txp + (s + 1) * KP;
                const float* q = typ + (s + 1) * KP;
                t1xa = r[lane]; t1xb = r[63 + lane]; t1xc = lc ? r[126 + lane] : 0.f;
                t1ya = q[lane]; t1yb = q[63 + lane]; t1yc = lc ? q[126 + lane] : 0.f;
            }

            // pose: each kp counted once
            if (s < len - 1) {
                float acc = fabsf(pa.x - t1xa) + fabsf(pa.y - t1ya);
                if (lane >= 1)       acc += fabsf(pb.x - t1xb) + fabsf(pb.y - t1yb);
                if (lane >= 1 && lc) acc += fabsf(pc.x - t1xc) + fabsf(pc.y - t1yc);
                pose += acc;
            }

            // e = pred - target (same row), bone via lane-shift
            float exa = pa.x - t0xa, eya = pa.y - t0ya;
            float exb = pb.x - t0xb, eyb = pb.y - t0yb;
            float exc = pc.x - t0xc, eyc = pc.y - t0yc;
            float nxa = __shfl_down(exa, 1, 64), nya = __shfl_down(eya, 1, 64);
            float nxb = __shfl_down(exb, 1, 64), nyb = __shfl_down(eyb, 1, 64);
            float nxc = __shfl_down(exc, 1, 64), nyc = __shfl_down(eyc, 1, 64);
            float acc = 0.f;
            if (lane < 63) {
                float dx = nxa - exa, dy = nya - eya; acc += dx * dx + dy * dy;
                float ex = nxb - exb, ey = nyb - eyb; acc += ex * ex + ey * ey;
            }
            if (lane < 10) {
                float dx = nxc - exc, dy = nyc - eyc; acc += dx * dx + dy * dy;
            }
            bone += acc;

            // roll: row s+1 target becomes next iteration's same-row target
            t0xa = t1xa; t0xb = t1xb; t0xc = t1xc;
            t0ya = t1ya; t0yb = t1yb; t0yc = t1yc;
        }
    }

    // wave reduce; no LDS, no barrier
    for (int off = 32; off > 0; off >>= 1) {
        pose += __shfl_down(pose, off, 64);
        bone += __shfl_down(bone, off, 64);
    }
    if (lane == 0) partials[w] = make_float2(pose, bone);
}

__global__ __launch_bounds__(1024) void t2p_final(
    const float2* __restrict__ partials,
    const int* __restrict__ tlen,
    float* __restrict__ out)
{
    const int t = threadIdx.x;
    float ps = 0.f, bs = 0.f;
    #pragma unroll
    for (int i = 0; i < NBLK / 1024; ++i) {      // 16 each
        float2 v = partials[t + i * 1024];
        ps += v.x; bs += v.y;
    }
    float pc = 0.f, mc = 0.f;
    if (t < BB) {
        int L = tlen[t];
        pc = (float)(L - 1);   // sum(pose_mask)
        mc = (float)L;         // sum(mask)
    }
    for (int off = 32; off > 0; off >>= 1) {
        ps += __shfl_down(ps, off, 64);
        bs += __shfl_down(bs, off, 64);
        pc += __shfl_down(pc, off, 64);
        mc += __shfl_down(mc, off, 64);
    }
    __shared__ float4 wsum[16];
    if ((t & 63) == 0) wsum[t >> 6] = make_float4(ps, bs, pc, mc);
    __syncthreads();
    if (t == 0) {
        float4 a = wsum[0];
        #pragma unroll
        for (int i = 1; i < 16; ++i) {
            a.x += wsum[i].x; a.y += wsum[i].y;
            a.z += wsum[i].z; a.w += wsum[i].w;
        }
        float pose_loss = a.x / (274.f * a.z);
        float bone_loss = (a.y * 0.5f) / ((136.f + 1e-8f) * a.w);
        out[0] = pose_loss + 0.1f * bone_loss;   // POSE_W=1, BONE_W=0.1
        out[1] = pose_loss;
        out[2] = bone_loss;
    }
}

extern "C" void kernel_launch(void* const* d_in, const int* in_sizes, int n_in,
                              void* d_out, int out_size, void* d_ws, size_t ws_size,
                              hipStream_t stream) {
    const float* pred = (const float*)d_in[0];   // [128,512,274] f32
    const float* tgt  = (const float*)d_in[1];   // [128,2,512,137] f32
    const int*   tlen = (const int*)d_in[2];     // [128] i32
    float* out = (float*)d_out;
    float2* partials = (float2*)d_ws;            // 16384 * 8 B = 128 KB

    t2p_main<<<NBLK, 64, 0, stream>>>(pred, tgt, tlen, partials);
    t2p_final<<<1, 1024, 0, stream>>>(partials, tlen, out);
}